// Round 6
// baseline (83.361 us; speedup 1.0000x reference)
//
#include <hip/hip_runtime.h>

#define GN   192
#define GNN  (GN * GN)
#define GTOT (GN * GN * GN)
#define LSTR 200                // dwords per LDS line array (4 head pad + 192 + halo + tail)
#define NSLOTS 256
#define NBLK (GN * 96)          // 18432 blocks: (i, j-pair)
#define CHUNK (NBLK / 8)        // 2304 (bijective XCD swizzle: 18432 % 8 == 0)

typedef float v2 __attribute__((ext_vector_type(2)));

// paired LDS read: elements idx and idx+LSTR (adjacent line arrays) -> ds_read2_b32
__device__ __forceinline__ v2 rd2(const float* a, int idx) {
    v2 r; r.x = a[idx]; r.y = a[idx + LSTR]; return r;
}

__global__ __launch_bounds__(192) void ns_loss_kernel(
    const float* __restrict__ u,      // (N,N,N,3)
    const float* __restrict__ uprev,  // (N,N,N,3)
    const float* __restrict__ p,      // (N,N,N)
    const float* __restrict__ rho,    // (N,N,N)
    const float* __restrict__ nu,
    const float* __restrict__ h,
    const float* __restrict__ dt,
    const float* __restrict__ grav,
    double* __restrict__ acc)
{
    // SoA LDS lines. u/p line order: 0:(i,jm) 1:(i,j0) 2:(i,j1) 3:(i,jp)
    //                                4:(i-1,j0) 5:(i-1,j1) 6:(i+1,j0) 7:(i+1,j1)
    // => every needed operand pair {val@j0, val@j1} sits in arrays LSTR apart.
    __shared__ __align__(16) float su[3][8][LSTR];
    __shared__ __align__(16) float sp[8][LSTR];
    __shared__ __align__(16) float sup[3][2][LSTR];
    __shared__ __align__(16) float srho[2][LSTR];

    const int t = threadIdx.x;
    const int d = blockIdx.x;
    const int o = (d & 7) * CHUNK + (d >> 3);
    const int i  = o / 96;
    const int b  = o - i * 96;
    const int j0 = 2 * b, j1 = 2 * b + 1;
    const int jmr = (j0 == 0) ? GN - 1 : j0 - 1;
    const int jpr = (j1 == GN - 1) ? 0 : j1 + 1;
    const int imr = (i == 0) ? GN - 1 : i - 1;
    const int ipr = (i == GN - 1) ? 0 : i + 1;

    float* SUX = &su[0][0][0];
    float* SUY = &su[1][0][0];
    float* SUZ = &su[2][0][0];

    // ---- staging: 192 threads = 4 groups x 48; each group stages 2 lines ----
    const int q = t / 48, s = t - q * 48;          // q in 0..3, s in 0..47
    const int row0 = (q == 0) ? jmr : (q == 1) ? j0 : (q == 2) ? j1 : jpr;
    const int base0 = (i * GN + row0) * GN;        // -> line slot q
    const int ri1 = (q < 2) ? imr : ipr;
    const int rj1 = (q & 1) ? j1 : j0;
    const int base1 = (ri1 * GN + rj1) * GN;       // -> line slot q+4

    // u: AoS float4-triple (4 cells / 12 floats) -> SoA transpose
    {
        const float4* g0 = (const float4*)(u + 3 * base0) + 3 * s;
        float4 a0 = g0[0], a1 = g0[1], a2 = g0[2];
        int wb = q * LSTR + 4 + 4 * s;
        SUX[wb] = a0.x; SUX[wb+1] = a0.w; SUX[wb+2] = a1.z; SUX[wb+3] = a2.y;
        SUY[wb] = a0.y; SUY[wb+1] = a1.x; SUY[wb+2] = a1.w; SUY[wb+3] = a2.z;
        SUZ[wb] = a0.z; SUZ[wb+1] = a1.y; SUZ[wb+2] = a2.x; SUZ[wb+3] = a2.w;

        const float4* g1 = (const float4*)(u + 3 * base1) + 3 * s;
        float4 b0 = g1[0], b1 = g1[1], b2 = g1[2];
        wb = (q + 4) * LSTR + 4 + 4 * s;
        SUX[wb] = b0.x; SUX[wb+1] = b0.w; SUX[wb+2] = b1.z; SUX[wb+3] = b2.y;
        SUY[wb] = b0.y; SUY[wb+1] = b1.x; SUY[wb+2] = b1.w; SUY[wb+3] = b2.z;
        SUZ[wb] = b0.z; SUZ[wb+1] = b1.y; SUZ[wb+2] = b2.x; SUZ[wb+3] = b2.w;
    }
    // p: straight float4 copies
    {
        float4 t0 = *((const float4*)(p + base0) + s);
        *(float4*)&sp[q][4 + 4 * s] = t0;
        float4 t1 = *((const float4*)(p + base1) + s);
        *(float4*)&sp[q + 4][4 + 4 * s] = t1;
    }

    if (t < 96) {
        // uprev lines j0,j1 (SoA transpose): groups q=0,1
        const int lu = q;                          // 0 or 1
        const int bu = (i * GN + j0 + lu) * GN;
        const float4* g = (const float4*)(uprev + 3 * bu) + 3 * s;
        float4 a0 = g[0], a1 = g[1], a2 = g[2];
        const int wb = lu * LSTR + 4 + 4 * s;
        float* PX = &sup[0][0][0]; float* PY = &sup[1][0][0]; float* PZ = &sup[2][0][0];
        PX[wb] = a0.x; PX[wb+1] = a0.w; PX[wb+2] = a1.z; PX[wb+3] = a2.y;
        PY[wb] = a0.y; PY[wb+1] = a1.x; PY[wb+2] = a1.w; PY[wb+3] = a2.z;
        PZ[wb] = a0.z; PZ[wb+1] = a1.y; PZ[wb+2] = a2.x; PZ[wb+3] = a2.w;
    } else {
        // rho lines j0,j1 (straight copy): 96 threads
        const int tt = t - 96;
        const int lr = tt / 48, s3 = tt - lr * 48;
        const int br = (i * GN + j0 + lr) * GN;
        *(float4*)&srho[lr][4 + 4 * s3] = *((const float4*)(rho + br) + s3);
    }

    // k-halos (uniform offsets for the compute phase): center u arrays (slots 1,2),
    // center p arrays (slots 1,2). phys[3] <- cell 191, phys[196] <- cell 0.
    if (t >= 96 && t < 108) {
        const int e = t - 96;                      // 0..11
        const int ell = 1 + (e / 6);               // slot 1 or 2
        const int r2 = e - (ell - 1) * 6;          // 0..5
        const int c = r2 >> 1, side = r2 & 1;      // component, side
        const int bb = (i * GN + ((ell == 1) ? j0 : j1)) * GN;
        float* SC = (c == 0) ? SUX : (c == 1) ? SUY : SUZ;
        SC[ell * LSTR + (side ? 196 : 3)] = u[3 * bb + (side ? c : 573 + c)];
    }
    if (t >= 108 && t < 112) {
        const int e = t - 108;                     // 0..3
        const int ell = 1 + (e >> 1), side = e & 1;
        const int bb = (i * GN + ((ell == 1) ? j0 : j1)) * GN;
        sp[ell][side ? 196 : 3] = p[bb + (side ? 0 : 191)];
    }

    // uniform scalars
    const float h0 = h[0], h1v = h[1], h2v = h[2];
    const float i2h0 = 0.5f * __builtin_amdgcn_rcpf(h0);
    const float i2h1 = 0.5f * __builtin_amdgcn_rcpf(h1v);
    const float i2h2 = 0.5f * __builtin_amdgcn_rcpf(h2v);
    const float ihs0 = __builtin_amdgcn_rcpf(h0 * h0);
    const float ihs1 = __builtin_amdgcn_rcpf(h1v * h1v);
    const float ihs2 = __builtin_amdgcn_rcpf(h2v * h2v);
    const float invdt = __builtin_amdgcn_rcpf(dt[0]);
    const float nu0 = nu[0];
    const float g0 = grav[0], g1v = grav[1], g2v = grav[2];
    const float s2h = 2.0f * (ihs0 + ihs1 + ihs2);

    __syncthreads();

    // ---- compute: thread t handles packed cell pair {(j0,k=t),(j1,k=t)} ----
    const int ph = t + 4;

    v2 ucx = rd2(SUX + LSTR, ph),     ucy = rd2(SUY + LSTR, ph),     ucz = rd2(SUZ + LSTR, ph);
    v2 zmx = rd2(SUX + LSTR, ph - 1), zmy = rd2(SUY + LSTR, ph - 1), zmz = rd2(SUZ + LSTR, ph - 1);
    v2 zpx = rd2(SUX + LSTR, ph + 1), zpy = rd2(SUY + LSTR, ph + 1), zpz = rd2(SUZ + LSTR, ph + 1);
    v2 ymx = rd2(SUX, ph),            ymy = rd2(SUY, ph),            ymz = rd2(SUZ, ph);            // j-1 pair
    v2 ypx = rd2(SUX + 2 * LSTR, ph), ypy = rd2(SUY + 2 * LSTR, ph), ypz = rd2(SUZ + 2 * LSTR, ph); // j+1 pair
    v2 xmx = rd2(SUX + 4 * LSTR, ph), xmy = rd2(SUY + 4 * LSTR, ph), xmz = rd2(SUZ + 4 * LSTR, ph); // i-1 pair
    v2 xpx = rd2(SUX + 6 * LSTR, ph), xpy = rd2(SUY + 6 * LSTR, ph), xpz = rd2(SUZ + 6 * LSTR, ph); // i+1 pair

    v2 dXx = (xpx - xmx) * i2h0, dXy = (xpy - xmy) * i2h0, dXz = (xpz - xmz) * i2h0;
    v2 dYx = (ypx - ymx) * i2h1, dYy = (ypy - ymy) * i2h1, dYz = (ypz - ymz) * i2h1;
    v2 dZx = (zpx - zmx) * i2h2, dZy = (zpy - zmy) * i2h2, dZz = (zpz - zmz) * i2h2;

    v2 lapx = (xpx + xmx) * ihs0 + (ypx + ymx) * ihs1 + (zpx + zmx) * ihs2 - ucx * s2h;
    v2 lapy = (xpy + xmy) * ihs0 + (ypy + ymy) * ihs1 + (zpy + zmy) * ihs2 - ucy * s2h;
    v2 lapz = (xpz + xmz) * ihs0 + (ypz + ymz) * ihs1 + (zpz + zmz) * ihs2 - ucz * s2h;

    v2 convx = ucx * dXx + ucy * dYx + ucz * dZx;
    v2 convy = ucx * dXy + ucy * dYy + ucz * dZy;
    v2 convz = ucx * dXz + ucy * dYz + ucz * dZz;

    v2 pkm = rd2(&sp[1][0], ph - 1), pkp = rd2(&sp[1][0], ph + 1);
    v2 pjm = rd2(&sp[0][0], ph),     pjp = rd2(&sp[2][0], ph);
    v2 pim = rd2(&sp[4][0], ph),     pip = rd2(&sp[6][0], ph);
    v2 dpx = (pip - pim) * i2h0;
    v2 dpy = (pjp - pjm) * i2h1;
    v2 dpz = (pkp - pkm) * i2h2;

    v2 rr = rd2(&srho[0][0], ph);
    v2 irho;
    irho.x = __builtin_amdgcn_rcpf(rr.x + 1e-8f);
    irho.y = __builtin_amdgcn_rcpf(rr.y + 1e-8f);

    v2 upx = rd2(&sup[0][0][0], ph), upy = rd2(&sup[1][0][0], ph), upz = rd2(&sup[2][0][0], ph);

    v2 Rx = (ucx - upx) * invdt + convx + dpx * irho - lapx * nu0 - g0;
    v2 Ry = (ucy - upy) * invdt + convy + dpy * irho - lapy * nu0 - g1v;
    v2 Rz = (ucz - upz) * invdt + convz + dpz * irho - lapz * nu0 - g2v;
    v2 Rc = dXx + dYy + dZz;

    v2 m2 = Rx * Rx + Ry * Ry + Rz * Rz;
    v2 c2 = Rc * Rc;
    double mom  = (double)m2.x + (double)m2.y;
    double cont = (double)c2.x + (double)c2.y;

    // ---- reduce: wave(64) shuffle, 3 waves via LDS, one atomic per block ----
    #pragma unroll
    for (int off = 32; off > 0; off >>= 1) {
        mom  += __shfl_down(mom, off);
        cont += __shfl_down(cont, off);
    }
    __shared__ double smom[3], scont[3];
    const int wid = t >> 6, lane = t & 63;
    if (lane == 0) { smom[wid] = mom; scont[wid] = cont; }
    __syncthreads();
    if (t == 0) {
        const double m = smom[0] + smom[1] + smom[2];
        const double c = scont[0] + scont[1] + scont[2];
        double* slot = acc + 2 * (blockIdx.x & (NSLOTS - 1));
        unsafeAtomicAdd(slot, m);
        unsafeAtomicAdd(slot + 1, c);
    }
}

__global__ __launch_bounds__(256) void ns_finalize_kernel(const double* __restrict__ acc,
                                                          float* __restrict__ out)
{
    const int tid = threadIdx.x;
    double mom = acc[2 * tid];
    double cont = acc[2 * tid + 1];
    #pragma unroll
    for (int off = 32; off > 0; off >>= 1) {
        mom  += __shfl_down(mom, off);
        cont += __shfl_down(cont, off);
    }
    __shared__ double smom[4], scont[4];
    const int wid = tid >> 6, lane = tid & 63;
    if (lane == 0) { smom[wid] = mom; scont[wid] = cont; }
    __syncthreads();
    if (tid == 0) {
        const double m = (smom[0] + smom[1] + smom[2] + smom[3]) / (double)GTOT;
        const double c = (scont[0] + scont[1] + scont[2] + scont[3]) / (double)GTOT;
        out[0] = (float)(m + 10.0 * c);
        out[1] = (float)m;
        out[2] = (float)c;
    }
}

extern "C" void kernel_launch(void* const* d_in, const int* in_sizes, int n_in,
                              void* d_out, int out_size, void* d_ws, size_t ws_size,
                              hipStream_t stream)
{
    const float* u     = (const float*)d_in[0];
    const float* uprev = (const float*)d_in[1];
    const float* p     = (const float*)d_in[2];
    const float* rho   = (const float*)d_in[3];
    const float* nu    = (const float*)d_in[4];
    const float* h     = (const float*)d_in[5];
    const float* dt    = (const float*)d_in[6];
    const float* grav  = (const float*)d_in[7];

    double* acc = (double*)d_ws;

    hipMemsetAsync(d_ws, 0, NSLOTS * 2 * sizeof(double), stream);

    ns_loss_kernel<<<NBLK, 192, 0, stream>>>(u, uprev, p, rho, nu, h, dt, grav, acc);
    ns_finalize_kernel<<<1, 256, 0, stream>>>(acc, (float*)d_out);
}

// Round 7
// 71.037 us; speedup vs baseline: 1.1735x; 1.1735x over previous
//
#include <hip/hip_runtime.h>

#define GN 192
#define GNN (GN * GN)
#define GTOT (GN * GN * GN)   // 7,077,888 = 27,648 * 256
#define NSLOTS 256

typedef float f4u __attribute__((ext_vector_type(4), aligned(4)));

// acc layout in d_ws: double acc[NSLOTS][2]  (mom, cont) = 4 KB

__global__ __launch_bounds__(256) void ns_loss_kernel(
    const float* __restrict__ u,      // (N,N,N,3)
    const float* __restrict__ uprev,  // (N,N,N,3)
    const float* __restrict__ p,      // (N,N,N)
    const float* __restrict__ rho,    // (N,N,N)
    const float* __restrict__ nu,     // (1,)
    const float* __restrict__ h,      // (3,)
    const float* __restrict__ dt,     // (1,)
    const float* __restrict__ grav,   // (3,)
    double* __restrict__ acc)
{
    const int idx = blockIdx.x * 256 + threadIdx.x;   // < GTOT exactly
    const int k = idx % GN;
    const int t = idx / GN;
    const int j = t % GN;
    const int i = t / GN;

    // uniform scalars (broadcast loads, cached)
    const float h0 = h[0], h1 = h[1], h2 = h[2];
    const float i2h0 = 0.5f / h0, i2h1 = 0.5f / h1, i2h2 = 0.5f / h2;
    const float ihs0 = 1.0f / (h0 * h0), ihs1 = 1.0f / (h1 * h1), ihs2 = 1.0f / (h2 * h2);
    const float invdt = 1.0f / dt[0];
    const float nu0 = nu[0];
    const float g0 = grav[0], g1 = grav[1], g2 = grav[2];

    // periodic neighbor cell indices
    const int kp = (k == GN - 1) ? idx - (GN - 1)       : idx + 1;
    const int km = (k == 0)      ? idx + (GN - 1)       : idx - 1;
    const int jp = (j == GN - 1) ? idx - (GN - 1) * GN  : idx + GN;
    const int jm = (j == 0)      ? idx + (GN - 1) * GN  : idx - GN;
    const int ip = (i == GN - 1) ? idx - (GN - 1) * GNN : idx + GNN;
    const int im = (i == 0)      ? idx + (GN - 1) * GNN : idx - GNN;

    // center + 6 neighbor velocity vectors: ONE dwordx4 each (4th lane unused)
    const f4u vc = *(const f4u*)(u + 3 * idx);
    const f4u vxp = *(const f4u*)(u + 3 * ip);
    const f4u vxm = *(const f4u*)(u + 3 * im);
    const f4u vyp = *(const f4u*)(u + 3 * jp);
    const f4u vym = *(const f4u*)(u + 3 * jm);
    const f4u vzp = *(const f4u*)(u + 3 * kp);
    const f4u vzm = *(const f4u*)(u + 3 * km);
    const f4u vup = *(const f4u*)(uprev + 3 * idx);

    const float ucx = vc.x,  ucy = vc.y,  ucz = vc.z;
    const float xpx = vxp.x, xpy = vxp.y, xpz = vxp.z;
    const float xmx = vxm.x, xmy = vxm.y, xmz = vxm.z;
    const float ypx = vyp.x, ypy = vyp.y, ypz = vyp.z;
    const float ymx = vym.x, ymy = vym.y, ymz = vym.z;
    const float zpx = vzp.x, zpy = vzp.y, zpz = vzp.z;
    const float zmx = vzm.x, zmy = vzm.y, zmz = vzm.z;

    // central differences: dA.c = d u_c / d axisA
    const float dXx = (xpx - xmx) * i2h0, dXy = (xpy - xmy) * i2h0, dXz = (xpz - xmz) * i2h0;
    const float dYx = (ypx - ymx) * i2h1, dYy = (ypy - ymy) * i2h1, dYz = (ypz - ymz) * i2h1;
    const float dZx = (zpx - zmx) * i2h2, dZy = (zpy - zmy) * i2h2, dZz = (zpz - zmz) * i2h2;

    // laplacian of each component
    const float lapx = (xpx - 2.0f * ucx + xmx) * ihs0 + (ypx - 2.0f * ucx + ymx) * ihs1 + (zpx - 2.0f * ucx + zmx) * ihs2;
    const float lapy = (xpy - 2.0f * ucy + xmy) * ihs0 + (ypy - 2.0f * ucy + ymy) * ihs1 + (zpy - 2.0f * ucy + zmy) * ihs2;
    const float lapz = (xpz - 2.0f * ucz + xmz) * ihs0 + (ypz - 2.0f * ucz + ymz) * ihs1 + (zpz - 2.0f * ucz + zmz) * ihs2;

    // convection
    const float convx = ucx * dXx + ucy * dYx + ucz * dZx;
    const float convy = ucx * dXy + ucy * dYy + ucz * dZy;
    const float convz = ucx * dXz + ucy * dYz + ucz * dZz;

    // pressure gradient (dense 4B-stride dword gathers)
    const float dpx = (p[ip] - p[im]) * i2h0;
    const float dpy = (p[jp] - p[jm]) * i2h1;
    const float dpz = (p[kp] - p[km]) * i2h2;

    const float inv_rho = __builtin_amdgcn_rcpf(rho[idx] + 1e-8f);

    const float dudtx = (ucx - vup.x) * invdt;
    const float dudty = (ucy - vup.y) * invdt;
    const float dudtz = (ucz - vup.z) * invdt;

    const float Rx = dudtx + convx + dpx * inv_rho - nu0 * lapx - g0;
    const float Ry = dudty + convy + dpy * inv_rho - nu0 * lapy - g1;
    const float Rz = dudtz + convz + dpz * inv_rho - nu0 * lapz - g2;
    const float Rc = dXx + dYy + dZz;

    double mom = (double)Rx * Rx + (double)Ry * Ry + (double)Rz * Rz;
    double cont = (double)Rc * Rc;

    // wave(64) reduce
    #pragma unroll
    for (int off = 32; off > 0; off >>= 1) {
        mom  += __shfl_down(mom, off);
        cont += __shfl_down(cont, off);
    }

    __shared__ double smom[4], scont[4];
    const int wid = threadIdx.x >> 6;
    const int lane = threadIdx.x & 63;
    if (lane == 0) { smom[wid] = mom; scont[wid] = cont; }
    __syncthreads();
    if (threadIdx.x == 0) {
        const double m = smom[0] + smom[1] + smom[2] + smom[3];
        const double c = scont[0] + scont[1] + scont[2] + scont[3];
        double* slot = acc + 2 * (blockIdx.x & (NSLOTS - 1));
        unsafeAtomicAdd(slot, m);
        unsafeAtomicAdd(slot + 1, c);
    }
}

__global__ __launch_bounds__(256) void ns_finalize_kernel(const double* __restrict__ acc,
                                                          float* __restrict__ out)
{
    const int tid = threadIdx.x;
    double mom = acc[2 * tid];
    double cont = acc[2 * tid + 1];
    #pragma unroll
    for (int off = 32; off > 0; off >>= 1) {
        mom  += __shfl_down(mom, off);
        cont += __shfl_down(cont, off);
    }
    __shared__ double smom[4], scont[4];
    const int wid = tid >> 6;
    const int lane = tid & 63;
    if (lane == 0) { smom[wid] = mom; scont[wid] = cont; }
    __syncthreads();
    if (tid == 0) {
        const double m = (smom[0] + smom[1] + smom[2] + smom[3]) / (double)GTOT;
        const double c = (scont[0] + scont[1] + scont[2] + scont[3]) / (double)GTOT;
        out[0] = (float)(m + 10.0 * c);
        out[1] = (float)m;
        out[2] = (float)c;
    }
}

extern "C" void kernel_launch(void* const* d_in, const int* in_sizes, int n_in,
                              void* d_out, int out_size, void* d_ws, size_t ws_size,
                              hipStream_t stream)
{
    const float* u     = (const float*)d_in[0];
    const float* uprev = (const float*)d_in[1];
    const float* p     = (const float*)d_in[2];
    const float* rho   = (const float*)d_in[3];
    const float* nu    = (const float*)d_in[4];
    const float* h     = (const float*)d_in[5];
    const float* dt    = (const float*)d_in[6];
    const float* grav  = (const float*)d_in[7];

    double* acc = (double*)d_ws;

    hipMemsetAsync(d_ws, 0, NSLOTS * 2 * sizeof(double), stream);

    ns_loss_kernel<<<GTOT / 256, 256, 0, stream>>>(u, uprev, p, rho, nu, h, dt, grav, acc);
    ns_finalize_kernel<<<1, 256, 0, stream>>>(acc, (float*)d_out);
}

// Round 8
// 65.623 us; speedup vs baseline: 1.2703x; 1.0825x over previous
//
#include <hip/hip_runtime.h>

#define GN 192
#define GNN (GN * GN)
#define GTOT (GN * GN * GN)   // 7,077,888 = 27,648 * 256
#define NSLOTS 256

// acc layout in d_ws: double acc[NSLOTS][2]  (mom, cont) = 4 KB

// Force a global_load_dwordx4 at a (possibly only 4B-aligned) address.
// gfx9+ runs with unaligned-access-mode; HW handles line-crossing lanes.
__device__ __forceinline__ float4 ld4(const float* ptr) {
    return *(const float4*)__builtin_assume_aligned(ptr, 16);
}

__global__ __launch_bounds__(256) void ns_loss_kernel(
    const float* __restrict__ u,      // (N,N,N,3)
    const float* __restrict__ uprev,  // (N,N,N,3)
    const float* __restrict__ p,      // (N,N,N)
    const float* __restrict__ rho,    // (N,N,N)
    const float* __restrict__ nu,     // (1,)
    const float* __restrict__ h,      // (3,)
    const float* __restrict__ dt,     // (1,)
    const float* __restrict__ grav,   // (3,)
    double* __restrict__ acc)
{
    const int idx = blockIdx.x * 256 + threadIdx.x;   // < GTOT exactly
    const int k = idx % GN;
    const int t = idx / GN;
    const int j = t % GN;
    const int i = t / GN;

    // uniform scalars (broadcast loads, cached)
    const float h0 = h[0], h1 = h[1], h2 = h[2];
    const float i2h0 = 0.5f / h0, i2h1 = 0.5f / h1, i2h2 = 0.5f / h2;
    const float ihs0 = 1.0f / (h0 * h0), ihs1 = 1.0f / (h1 * h1), ihs2 = 1.0f / (h2 * h2);
    const float invdt = 1.0f / dt[0];
    const float nu0 = nu[0];
    const float g0 = grav[0], g1 = grav[1], g2 = grav[2];

    // periodic neighbor cell indices
    const int kp = (k == GN - 1) ? idx - (GN - 1)       : idx + 1;
    const int km = (k == 0)      ? idx + (GN - 1)       : idx - 1;
    const int jp = (j == GN - 1) ? idx - (GN - 1) * GN  : idx + GN;
    const int jm = (j == 0)      ? idx + (GN - 1) * GN  : idx - GN;
    const int ip = (i == GN - 1) ? idx - (GN - 1) * GNN : idx + GNN;
    const int im = (i == 0)      ? idx + (GN - 1) * GNN : idx - GNN;

    // center + 6 neighbor velocity vectors: ONE dwordx4 each (4th dword unused)
    const float4 vc  = ld4(u + 3 * idx);
    const float4 vxp = ld4(u + 3 * ip);
    const float4 vxm = ld4(u + 3 * im);
    const float4 vyp = ld4(u + 3 * jp);
    const float4 vym = ld4(u + 3 * jm);
    const float4 vzp = ld4(u + 3 * kp);
    const float4 vzm = ld4(u + 3 * km);
    const float4 vup = ld4(uprev + 3 * idx);

    const float ucx = vc.x,  ucy = vc.y,  ucz = vc.z;
    const float xpx = vxp.x, xpy = vxp.y, xpz = vxp.z;
    const float xmx = vxm.x, xmy = vxm.y, xmz = vxm.z;
    const float ypx = vyp.x, ypy = vyp.y, ypz = vyp.z;
    const float ymx = vym.x, ymy = vym.y, ymz = vym.z;
    const float zpx = vzp.x, zpy = vzp.y, zpz = vzp.z;
    const float zmx = vzm.x, zmy = vzm.y, zmz = vzm.z;

    // central differences: dA.c = d u_c / d axisA
    const float dXx = (xpx - xmx) * i2h0, dXy = (xpy - xmy) * i2h0, dXz = (xpz - xmz) * i2h0;
    const float dYx = (ypx - ymx) * i2h1, dYy = (ypy - ymy) * i2h1, dYz = (ypz - ymz) * i2h1;
    const float dZx = (zpx - zmx) * i2h2, dZy = (zpy - zmy) * i2h2, dZz = (zpz - zmz) * i2h2;

    // laplacian of each component
    const float lapx = (xpx - 2.0f * ucx + xmx) * ihs0 + (ypx - 2.0f * ucx + ymx) * ihs1 + (zpx - 2.0f * ucx + zmx) * ihs2;
    const float lapy = (xpy - 2.0f * ucy + xmy) * ihs0 + (ypy - 2.0f * ucy + ymy) * ihs1 + (zpy - 2.0f * ucy + zmy) * ihs2;
    const float lapz = (xpz - 2.0f * ucz + xmz) * ihs0 + (ypz - 2.0f * ucz + ymz) * ihs1 + (zpz - 2.0f * ucz + zmz) * ihs2;

    // convection
    const float convx = ucx * dXx + ucy * dYx + ucz * dZx;
    const float convy = ucx * dXy + ucy * dYy + ucz * dZy;
    const float convz = ucx * dXz + ucy * dYz + ucz * dZz;

    // pressure gradient (dense 4B-stride dword gathers — already line-efficient)
    const float dpx = (p[ip] - p[im]) * i2h0;
    const float dpy = (p[jp] - p[jm]) * i2h1;
    const float dpz = (p[kp] - p[km]) * i2h2;

    const float inv_rho = __builtin_amdgcn_rcpf(rho[idx] + 1e-8f);

    const float dudtx = (ucx - vup.x) * invdt;
    const float dudty = (ucy - vup.y) * invdt;
    const float dudtz = (ucz - vup.z) * invdt;

    const float Rx = dudtx + convx + dpx * inv_rho - nu0 * lapx - g0;
    const float Ry = dudty + convy + dpy * inv_rho - nu0 * lapy - g1;
    const float Rz = dudtz + convz + dpz * inv_rho - nu0 * lapz - g2;
    const float Rc = dXx + dYy + dZz;

    double mom = (double)Rx * Rx + (double)Ry * Ry + (double)Rz * Rz;
    double cont = (double)Rc * Rc;

    // wave(64) reduce
    #pragma unroll
    for (int off = 32; off > 0; off >>= 1) {
        mom  += __shfl_down(mom, off);
        cont += __shfl_down(cont, off);
    }

    __shared__ double smom[4], scont[4];
    const int wid = threadIdx.x >> 6;
    const int lane = threadIdx.x & 63;
    if (lane == 0) { smom[wid] = mom; scont[wid] = cont; }
    __syncthreads();
    if (threadIdx.x == 0) {
        const double m = smom[0] + smom[1] + smom[2] + smom[3];
        const double c = scont[0] + scont[1] + scont[2] + scont[3];
        double* slot = acc + 2 * (blockIdx.x & (NSLOTS - 1));
        unsafeAtomicAdd(slot, m);
        unsafeAtomicAdd(slot + 1, c);
    }
}

__global__ __launch_bounds__(256) void ns_finalize_kernel(const double* __restrict__ acc,
                                                          float* __restrict__ out)
{
    const int tid = threadIdx.x;
    double mom = acc[2 * tid];
    double cont = acc[2 * tid + 1];
    #pragma unroll
    for (int off = 32; off > 0; off >>= 1) {
        mom  += __shfl_down(mom, off);
        cont += __shfl_down(cont, off);
    }
    __shared__ double smom[4], scont[4];
    const int wid = tid >> 6;
    const int lane = tid & 63;
    if (lane == 0) { smom[wid] = mom; scont[wid] = cont; }
    __syncthreads();
    if (tid == 0) {
        const double m = (smom[0] + smom[1] + smom[2] + smom[3]) / (double)GTOT;
        const double c = (scont[0] + scont[1] + scont[2] + scont[3]) / (double)GTOT;
        out[0] = (float)(m + 10.0 * c);
        out[1] = (float)m;
        out[2] = (float)c;
    }
}

extern "C" void kernel_launch(void* const* d_in, const int* in_sizes, int n_in,
                              void* d_out, int out_size, void* d_ws, size_t ws_size,
                              hipStream_t stream)
{
    const float* u     = (const float*)d_in[0];
    const float* uprev = (const float*)d_in[1];
    const float* p     = (const float*)d_in[2];
    const float* rho   = (const float*)d_in[3];
    const float* nu    = (const float*)d_in[4];
    const float* h     = (const float*)d_in[5];
    const float* dt    = (const float*)d_in[6];
    const float* grav  = (const float*)d_in[7];

    double* acc = (double*)d_ws;

    hipMemsetAsync(d_ws, 0, NSLOTS * 2 * sizeof(double), stream);

    ns_loss_kernel<<<GTOT / 256, 256, 0, stream>>>(u, uprev, p, rho, nu, h, dt, grav, acc);
    ns_finalize_kernel<<<1, 256, 0, stream>>>(acc, (float*)d_out);
}